// Round 2
// baseline (180.648 us; speedup 1.0000x reference)
//
#include <hip/hip_runtime.h>
#include <stdint.h>

#define N_TOK 16384
#define F_DIM 128
#define U_DIM 64
#define E_DIM 32

typedef __bf16 bf16x8 __attribute__((ext_vector_type(8)));
typedef float  floatx4 __attribute__((ext_vector_type(4)));

#define MFMA16(a, b, c) __builtin_amdgcn_mfma_f32_16x16x32_bf16((a), (b), (c), 0, 0, 0)

__device__ __forceinline__ unsigned short f2bf(float f) {
  union { float f; unsigned u; } v; v.f = f;
  unsigned r = v.u + 0x7FFFu + ((v.u >> 16) & 1u);  // RNE
  return (unsigned short)(r >> 16);
}

// 8 fp32 -> packed bf16x8 bits as uint4 (for LDS store)
__device__ __forceinline__ uint4 pack8(const float* w) {
  union { unsigned short us[8]; uint4 q; } p;
#pragma unroll
  for (int j = 0; j < 8; j++) p.us[j] = f2bf(w[j]);
  return p.q;
}

// 8 fp32 -> bf16x8 (for direct MFMA operand)
__device__ __forceinline__ bf16x8 cvt8(const float* w) {
  union { unsigned short us[8]; bf16x8 v; } p;
#pragma unroll
  for (int j = 0; j < 8; j++) p.us[j] = f2bf(w[j]);
  return p.v;
}

// ---------------------------------------------------------------------------
// Single fused kernel: 256 wgs x 512 thr (8 waves, 2/SIMD). No workspace, no
// prep kernel: each block converts We fp32->bf16 cooperatively, one expert
// ahead, into a double-buffered LDS tile (16 KB/expert). Fragment values are
// bit-identical to the old wsWe/wsWg layouts.
//   B LDS elem idx: (ks*4+quad)*512 + u*8 + j == We[e][ks*32+quad*8+j][u]
// Staging: thread covers groups kq=wid and kq=wid+8 (kq=ks*4+quad), i.e.
// rows f=kq*8..kq*8+7 at column u=lane -> 8 coalesced 256B row reads.
// One barrier per expert; prefetch loads issued a full iteration early.
// ---------------------------------------------------------------------------
__global__ __launch_bounds__(512, 2) void moe_fused(
    const float* __restrict__ x,
    const float* __restrict__ Wg,
    const float* __restrict__ bg,
    const float* __restrict__ We,
    const float* __restrict__ be,
    float* __restrict__ out) {
  __shared__ __align__(16) unsigned short Xs[64 * 136];   // padded rows
  __shared__ __align__(16) float Gs[E_DIM][68];           // gate [e][row]
  __shared__ __align__(16) unsigned short Bs[2][8192];    // expert dbuf

  const int tid  = threadIdx.x;
  const int lane = tid & 63;
  const int wid  = tid >> 6;       // 0..7
  const int quad = lane >> 4;
  const int l15  = lane & 15;
  const int wr   = wid >> 2;       // 0..1 row half
  const int wc   = wid & 3;        // 0..3 u quarter
  const int u    = wc * 16 + l15;
  const int base = blockIdx.x * 64;

  // B staging source pointers (group kq=wid and kq=wid+8; f0 = kq*8)
  const float* wsrc0 = We + wid * 512 + lane;
  const float* wsrc1 = We + (wid + 8) * 512 + lane;

  // ---- issue B(e=0) fp32 loads first (L2 latency hides under X staging)
  float w0[8], w1[8];
#pragma unroll
  for (int j = 0; j < 8; j++) { w0[j] = wsrc0[j * 64]; w1[j] = wsrc1[j * 64]; }

  // ---- issue gate weight loads (one-time): wave = (rg=row group, et=expert half)
  const int et = wid & 1;
  const int rg = wid >> 1;
  float wgv[4][8];
#pragma unroll
  for (int ks = 0; ks < 4; ks++)
#pragma unroll
    for (int j = 0; j < 8; j++)
      wgv[ks][j] = Wg[(ks * 32 + quad * 8 + j) * 32 + et * 16 + l15];

  float bev = be[u];  // bias for expert 0

  // ---- stage X tile (fp32 -> bf16) into LDS: 512 thr x 16 floats = 64x128
  {
    const int row = tid >> 3;
    const int c16 = tid & 7;
    const float4* src = (const float4*)(x + (size_t)(base + row) * F_DIM + c16 * 16);
    float4 v0 = src[0], v1 = src[1], v2 = src[2], v3 = src[3];
    union { unsigned short us[16]; uint4 q[2]; } pk;
    pk.us[0]  = f2bf(v0.x); pk.us[1]  = f2bf(v0.y); pk.us[2]  = f2bf(v0.z); pk.us[3]  = f2bf(v0.w);
    pk.us[4]  = f2bf(v1.x); pk.us[5]  = f2bf(v1.y); pk.us[6]  = f2bf(v1.z); pk.us[7]  = f2bf(v1.w);
    pk.us[8]  = f2bf(v2.x); pk.us[9]  = f2bf(v2.y); pk.us[10] = f2bf(v2.z); pk.us[11] = f2bf(v2.w);
    pk.us[12] = f2bf(v3.x); pk.us[13] = f2bf(v3.y); pk.us[14] = f2bf(v3.z); pk.us[15] = f2bf(v3.w);
    uint4* dst = (uint4*)&Xs[row * 136 + c16 * 16];
    dst[0] = pk.q[0];
    dst[1] = pk.q[1];
  }
  __syncthreads();  // barrier 1: Xs ready

  // ---- publish B(0) to Bs[0]; issue loads for B(1)
  *(uint4*)&Bs[0][tid * 8]        = pack8(w0);
  *(uint4*)&Bs[0][tid * 8 + 4096] = pack8(w1);
#pragma unroll
  for (int j = 0; j < 8; j++) {
    w0[j] = wsrc0[8192 + j * 64];
    w1[j] = wsrc1[8192 + j * 64];
  }

  // ---- gate: wave (rg, et) computes rows rg*16.., experts et*16..
  {
    bf16x8 ag[4];
#pragma unroll
    for (int ks = 0; ks < 4; ks++)
      ag[ks] = *(const bf16x8*)&Xs[(rg * 16 + l15) * 136 + ks * 32 + quad * 8];
    floatx4 g = {0.f, 0.f, 0.f, 0.f};
#pragma unroll
    for (int ks = 0; ks < 4; ks++) {
      bf16x8 wb = cvt8(wgv[ks]);
      g = MFMA16(ag[ks], wb, g);
    }
    float bgv = bg[et * 16 + l15];
#pragma unroll
    for (int r = 0; r < 4; r++)
      Gs[et * 16 + l15][rg * 16 + quad * 4 + r] = g[r] + bgv;
  }

  // ---- preload this wave's A fragments (Xs never re-read after)
  bf16x8 a[2][4];
#pragma unroll
  for (int mb = 0; mb < 2; mb++)
#pragma unroll
    for (int ks = 0; ks < 4; ks++)
      a[mb][ks] = *(const bf16x8*)&Xs[(wr * 32 + mb * 16 + l15) * 136 + ks * 32 + quad * 8];
  __syncthreads();  // barrier 2: Gs + Bs[0] ready

  float oacc[8];
#pragma unroll
  for (int i = 0; i < 8; i++) oacc[i] = 0.f;

  float4 gbuf[2][2];
#pragma unroll
  for (int mb = 0; mb < 2; mb++)
    gbuf[0][mb] = *(const float4*)&Gs[0][wr * 32 + mb * 16 + quad * 4];

  // ---- expert loop: one barrier per expert
#pragma unroll
  for (int e = 0; e < E_DIM; ++e) {
    const int p  = e & 1;
    const int gp = e & 1;

    // fragment reads for expert e (inherent-minimum bank pattern for b128)
    bf16x8 bb[4];
#pragma unroll
    for (int ks = 0; ks < 4; ks++)
      bb[ks] = *(const bf16x8*)&Bs[p][(ks * 4 + quad) * 512 + u * 8];

    // publish B(e+1) (regs loaded last iter), then issue loads for B(e+2)
    if (e + 1 < E_DIM) {
      *(uint4*)&Bs[p ^ 1][tid * 8]        = pack8(w0);
      *(uint4*)&Bs[p ^ 1][tid * 8 + 4096] = pack8(w1);
    }
    if (e + 2 < E_DIM) {
#pragma unroll
      for (int j = 0; j < 8; j++) {
        w0[j] = wsrc0[(e + 2) * 8192 + j * 64];
        w1[j] = wsrc1[(e + 2) * 8192 + j * 64];
      }
    }
    float bev_nxt = (e + 1 < E_DIM) ? be[(e + 1) * U_DIM + u] : 0.f;

    // gate rows for e+1 (hidden under e's MFMAs)
    if (e + 1 < E_DIM) {
#pragma unroll
      for (int mb = 0; mb < 2; mb++)
        gbuf[gp ^ 1][mb] = *(const float4*)&Gs[e + 1][wr * 32 + mb * 16 + quad * 4];
    }

    floatx4 h[2];
#pragma unroll
    for (int mb = 0; mb < 2; mb++) h[mb] = {0.f, 0.f, 0.f, 0.f};
#pragma unroll
    for (int ks = 0; ks < 4; ks++)
#pragma unroll
      for (int mb = 0; mb < 2; mb++)
        h[mb] = MFMA16(a[mb][ks], bb[ks], h[mb]);

    // epilogue: out += gate * leaky(h + be)
#pragma unroll
    for (int mb = 0; mb < 2; mb++) {
      const float4 g4 = gbuf[gp][mb];
      const float gr[4] = {g4.x, g4.y, g4.z, g4.w};
#pragma unroll
      for (int r = 0; r < 4; r++) {
        float t = h[mb][r] + bev;
        t = fmaxf(t, 0.01f * t);
        oacc[mb * 4 + r] = fmaf(gr[r], t, oacc[mb * 4 + r]);
      }
    }
    bev = bev_nxt;

    if (e + 1 < E_DIM) __syncthreads();  // Bs[p^1] published for next iter
  }

  // ---- store
#pragma unroll
  for (int mb = 0; mb < 2; mb++)
#pragma unroll
    for (int r = 0; r < 4; r++)
      out[(size_t)(base + wr * 32 + mb * 16 + quad * 4 + r) * U_DIM + u] = oacc[mb * 4 + r];
}

extern "C" void kernel_launch(void* const* d_in, const int* in_sizes, int n_in,
                              void* d_out, int out_size, void* d_ws, size_t ws_size,
                              hipStream_t stream) {
  const float* x  = (const float*)d_in[0];
  const float* Wg = (const float*)d_in[1];
  const float* bg = (const float*)d_in[2];
  const float* We = (const float*)d_in[3];
  const float* be = (const float*)d_in[4];
  (void)in_sizes; (void)n_in; (void)out_size; (void)d_ws; (void)ws_size;

  moe_fused<<<N_TOK / 64, 512, 0, stream>>>(x, Wg, bg, We, be, (float*)d_out);
}

// Round 3
// 84.234 us; speedup vs baseline: 2.1446x; 2.1446x over previous
//
#include <hip/hip_runtime.h>
#include <stdint.h>

#define N_TOK 16384
#define F_DIM 128
#define U_DIM 64
#define E_DIM 32

typedef __bf16 bf16x8 __attribute__((ext_vector_type(8)));
typedef float  floatx4 __attribute__((ext_vector_type(4)));

#define MFMA16(a, b, c) __builtin_amdgcn_mfma_f32_16x16x32_bf16((a), (b), (c), 0, 0, 0)

__device__ __forceinline__ unsigned short f2bf(float f) {
  union { float f; unsigned u; } v; v.f = f;
  unsigned r = v.u + 0x7FFFu + ((v.u >> 16) & 1u);  // RNE
  return (unsigned short)(r >> 16);
}

// 16-byte global -> LDS direct DMA (vmcnt-tracked)
__device__ __forceinline__ void gload_lds16(const void* g, void* l) {
  __builtin_amdgcn_global_load_lds(
      (const __attribute__((address_space(1))) unsigned int*)g,
      (__attribute__((address_space(3))) unsigned int*)l, 16, 0, 0);
}

// ---------------------------------------------------------------------------
// Prep (verified): fragment-linear bf16 weights in ws.
//  wsWe elem idx: ((e*4+ks)*4+quad)*512 + u*8 + j   == We[e][ks*32+quad*8+j][u]
//  wsWg elem idx: ((et*4+ks)*64 + lane)*8 + j       == Wg[ks*32+(lane>>4)*8+j][et*16+(lane&15)]
// ---------------------------------------------------------------------------
__global__ __launch_bounds__(256) void moe_prep(
    const float* __restrict__ Wg, const float* __restrict__ We,
    unsigned short* __restrict__ wsWe, unsigned short* __restrict__ wsWg) {
  int t = blockIdx.x * 256 + threadIdx.x;
  if (t < 32768) {
    int u = t & 63, quad = (t >> 6) & 3, ks = (t >> 8) & 3, e = t >> 10;
    int f0 = ks * 32 + quad * 8;
    const float* src = We + e * 8192 + f0 * 64 + u;
    union { unsigned short us[8]; uint4 q; } p;
#pragma unroll
    for (int j = 0; j < 8; j++) p.us[j] = f2bf(src[j * 64]);
    *(uint4*)(wsWe + t * 8) = p.q;
  } else if (t < 32768 + 512) {
    int t2 = t - 32768;
    int l15 = t2 & 15, quad = (t2 >> 4) & 3, ks = (t2 >> 6) & 3, et = t2 >> 8;
    int e = et * 16 + l15, f0 = ks * 32 + quad * 8;
    union { unsigned short us[8]; uint4 q; } p;
#pragma unroll
    for (int j = 0; j < 8; j++) p.us[j] = f2bf(Wg[(f0 + j) * 32 + e]);
    *(uint4*)(wsWg + t2 * 8) = p.q;
  }
}

// ---------------------------------------------------------------------------
// Main: 256 wgs x 512 thr (8 waves). B staged via global_load_lds into a
// TRIPLE-buffered LDS ring; ONE raw s_barrier + ONE counted s_waitcnt
// vmcnt(2) per expert (loads stay ~1.3 iters in flight, never drained).
// LDS = 64 KB exactly: buffer 2 aliases the Xs region (Xs dead after A-frag
// preload, which completes before the first DMA into it is issued).
// Xs is XOR-swizzled (chunk ^= row&7) instead of padded: conflict-free
// fragment reads without breaking anything.
// Loop invariant (top of iter e): pr0=buf(e%3) holds B(e) complete (all
// waves, via prev iter's vmcnt(2)+barrier), pr1 holds B(e+1) in flight,
// pr2=buf((e+2)%3) is free (last read iter e-1, protected by its barrier).
// ---------------------------------------------------------------------------
__global__ __launch_bounds__(512, 2) void moe_main(
    const float* __restrict__ x,
    const float* __restrict__ bg,
    const float* __restrict__ be,
    const unsigned short* __restrict__ wsWe,
    const unsigned short* __restrict__ wsWg,
    float* __restrict__ out) {
  __shared__ __align__(16) char smem[65536];
  unsigned short* Xs  = (unsigned short*)smem;           // [64][128] swizzled (aliases Bs2)
  unsigned short* Bs0 = (unsigned short*)(smem + 16384);
  unsigned short* Bs1 = (unsigned short*)(smem + 32768);
  unsigned short* Bs2 = (unsigned short*)smem;
  float* Gs  = (float*)(smem + 49152);                   // [32][64]
  float* BeS = (float*)(smem + 57344);                   // [32][64]

  const int tid  = threadIdx.x;
  const int lane = tid & 63;
  const int wid  = tid >> 6;       // 0..7
  const int quad = lane >> 4;
  const int l15  = lane & 15;
  const int wr   = wid >> 2;       // 0..1 row half
  const int wc   = wid & 3;        // 0..3 u quarter
  const int u    = wc * 16 + l15;
  const int base = blockIdx.x * 64;

  const char* gW = (const char*)wsWe;  // expert-e tile at gW + e*16384, linear bytes

  // ---- issue B(0), B(1) DMA immediately (land well before sync2's drain)
  gload_lds16(gW + tid * 16,               Bs0 + tid * 8);
  gload_lds16(gW + 8192 + tid * 16,        Bs0 + tid * 8 + 4096);
  gload_lds16(gW + 16384 + tid * 16,       Bs1 + tid * 8);
  gload_lds16(gW + 16384 + 8192 + tid * 16, Bs1 + tid * 8 + 4096);

  // ---- stage be into LDS (avoids dynamic register indexing in loop)
  ((float4*)BeS)[tid] = ((const float4*)be)[tid];

  // ---- stage X tile (fp32 -> bf16), XOR-swizzled 16B chunks
  {
    const int row = tid >> 3;
    const int c16 = tid & 7;
    const float4* src = (const float4*)(x + (size_t)(base + row) * F_DIM + c16 * 16);
    float4 v0 = src[0], v1 = src[1], v2 = src[2], v3 = src[3];
    union { unsigned short us[16]; uint4 q[2]; } pk;
    pk.us[0]  = f2bf(v0.x); pk.us[1]  = f2bf(v0.y); pk.us[2]  = f2bf(v0.z); pk.us[3]  = f2bf(v0.w);
    pk.us[4]  = f2bf(v1.x); pk.us[5]  = f2bf(v1.y); pk.us[6]  = f2bf(v1.z); pk.us[7]  = f2bf(v1.w);
    pk.us[8]  = f2bf(v2.x); pk.us[9]  = f2bf(v2.y); pk.us[10] = f2bf(v2.z); pk.us[11] = f2bf(v2.w);
    pk.us[12] = f2bf(v3.x); pk.us[13] = f2bf(v3.y); pk.us[14] = f2bf(v3.z); pk.us[15] = f2bf(v3.w);
    const int sw = row & 7;
    *(uint4*)&Xs[row * 128 + ((c16 * 2) ^ sw) * 8]     = pk.q[0];
    *(uint4*)&Xs[row * 128 + ((c16 * 2 + 1) ^ sw) * 8] = pk.q[1];
  }
  __syncthreads();  // sync1: Xs + BeS ready

  // ---- gate: wave (rg, et); writes Gs[e][token-row]
  {
    const int rg = wid >> 1;
    const int et = wid & 1;
    bf16x8 ag[4];
#pragma unroll
    for (int ks = 0; ks < 4; ks++) {
      const int row = rg * 16 + l15;
      ag[ks] = *(const bf16x8*)&Xs[row * 128 + (((ks * 4 + quad) ^ (row & 7))) * 8];
    }
    floatx4 g = {0.f, 0.f, 0.f, 0.f};
#pragma unroll
    for (int ks = 0; ks < 4; ks++) {
      bf16x8 wb = *(const bf16x8*)(wsWg + (size_t)((et * 4 + ks) * 64 + lane) * 8);
      g = MFMA16(ag[ks], wb, g);
    }
    float bgv = bg[et * 16 + l15];
#pragma unroll
    for (int r = 0; r < 4; r++)
      Gs[(et * 16 + l15) * 64 + rg * 16 + quad * 4 + r] = g[r] + bgv;
  }

  // ---- preload this wave's A fragments (Xs dead afterward)
  bf16x8 a[2][4];
#pragma unroll
  for (int mb = 0; mb < 2; mb++)
#pragma unroll
    for (int ks = 0; ks < 4; ks++) {
      const int row = wr * 32 + mb * 16 + l15;
      a[mb][ks] = *(const bf16x8*)&Xs[row * 128 + (((ks * 4 + quad) ^ (row & 7))) * 8];
    }
  __syncthreads();  // sync2: Gs ready; all Xs reads done; B(0),B(1) landed (full drain)

  float oacc[8];
#pragma unroll
  for (int i = 0; i < 8; i++) oacc[i] = 0.f;

  const unsigned short* pr0 = Bs0;  // buf(e%3)
  const unsigned short* pr1 = Bs1;  // buf((e+1)%3)
  const unsigned short* pr2 = Bs2;  // buf((e+2)%3) — DMA target
  const char* gsrc = gW + 2 * 16384;

#pragma unroll 3
  for (int e = 0; e < 30; ++e) {
    // top: issue B(e+2) into pr2 (free: last read iter e-1, barrier-protected)
    gload_lds16(gsrc + tid * 16,        (void*)(pr2 + tid * 8));
    gload_lds16(gsrc + 8192 + tid * 16, (void*)(pr2 + tid * 8 + 4096));
    gsrc += 16384;

    // reads (B(e) guaranteed complete by prev iter's vmcnt(2)+barrier)
    bf16x8 bb[4];
#pragma unroll
    for (int ks = 0; ks < 4; ks++)
      bb[ks] = *(const bf16x8*)(pr0 + (ks * 4 + quad) * 512 + u * 8);
    float bev = BeS[e * 64 + u];
    float4 gc[2];
#pragma unroll
    for (int mb = 0; mb < 2; mb++)
      gc[mb] = *(const float4*)&Gs[e * 64 + wr * 32 + mb * 16 + quad * 4];

    // pin ds_reads complete BEFORE the end-of-iter barrier (rule #18)
    asm volatile("s_waitcnt lgkmcnt(0)" ::: "memory");
    __builtin_amdgcn_sched_barrier(0);

    floatx4 h[2];
#pragma unroll
    for (int mb = 0; mb < 2; mb++) h[mb] = {0.f, 0.f, 0.f, 0.f};
#pragma unroll
    for (int ks = 0; ks < 4; ks++)
#pragma unroll
      for (int mb = 0; mb < 2; mb++)
        h[mb] = MFMA16(a[mb][ks], bb[ks], h[mb]);

#pragma unroll
    for (int mb = 0; mb < 2; mb++) {
      const float gr[4] = {gc[mb].x, gc[mb].y, gc[mb].z, gc[mb].w};
#pragma unroll
      for (int r = 0; r < 4; r++) {
        float t = h[mb][r] + bev;
        t = fmaxf(t, 0.01f * t);
        oacc[mb * 4 + r] = fmaf(gr[r], t, oacc[mb * 4 + r]);
      }
    }

    // counted wait: leaves B(e+2)'s 2 loads in flight; B(e+1) landed
    asm volatile("s_waitcnt vmcnt(2)" ::: "memory");
    __builtin_amdgcn_s_barrier();

    const unsigned short* t0 = pr0; pr0 = pr1; pr1 = pr2; pr2 = t0;
  }

  // ---- e = 30 (no issue; full drain so B(31) is ready)
  {
    bf16x8 bb[4];
#pragma unroll
    for (int ks = 0; ks < 4; ks++)
      bb[ks] = *(const bf16x8*)(pr0 + (ks * 4 + quad) * 512 + u * 8);
    float bev = BeS[30 * 64 + u];
    float4 gc[2];
#pragma unroll
    for (int mb = 0; mb < 2; mb++)
      gc[mb] = *(const float4*)&Gs[30 * 64 + wr * 32 + mb * 16 + quad * 4];
    asm volatile("s_waitcnt lgkmcnt(0)" ::: "memory");
    __builtin_amdgcn_sched_barrier(0);
    floatx4 h[2];
#pragma unroll
    for (int mb = 0; mb < 2; mb++) h[mb] = {0.f, 0.f, 0.f, 0.f};
#pragma unroll
    for (int ks = 0; ks < 4; ks++)
#pragma unroll
      for (int mb = 0; mb < 2; mb++)
        h[mb] = MFMA16(a[mb][ks], bb[ks], h[mb]);
#pragma unroll
    for (int mb = 0; mb < 2; mb++) {
      const float gr[4] = {gc[mb].x, gc[mb].y, gc[mb].z, gc[mb].w};
#pragma unroll
      for (int r = 0; r < 4; r++) {
        float t = h[mb][r] + bev;
        t = fmaxf(t, 0.01f * t);
        oacc[mb * 4 + r] = fmaf(gr[r], t, oacc[mb * 4 + r]);
      }
    }
    asm volatile("s_waitcnt vmcnt(0)" ::: "memory");
    __builtin_amdgcn_s_barrier();
  }

  // ---- e = 31 (pr1 holds B(31); no more syncs)
  {
    bf16x8 bb[4];
#pragma unroll
    for (int ks = 0; ks < 4; ks++)
      bb[ks] = *(const bf16x8*)(pr1 + (ks * 4 + quad) * 512 + u * 8);
    float bev = BeS[31 * 64 + u];
    float4 gc[2];
#pragma unroll
    for (int mb = 0; mb < 2; mb++)
      gc[mb] = *(const float4*)&Gs[31 * 64 + wr * 32 + mb * 16 + quad * 4];
    floatx4 h[2];
#pragma unroll
    for (int mb = 0; mb < 2; mb++) h[mb] = {0.f, 0.f, 0.f, 0.f};
#pragma unroll
    for (int ks = 0; ks < 4; ks++)
#pragma unroll
      for (int mb = 0; mb < 2; mb++)
        h[mb] = MFMA16(a[mb][ks], bb[ks], h[mb]);
#pragma unroll
    for (int mb = 0; mb < 2; mb++) {
      const float gr[4] = {gc[mb].x, gc[mb].y, gc[mb].z, gc[mb].w};
#pragma unroll
      for (int r = 0; r < 4; r++) {
        float t = h[mb][r] + bev;
        t = fmaxf(t, 0.01f * t);
        oacc[mb * 4 + r] = fmaf(gr[r], t, oacc[mb * 4 + r]);
      }
    }
  }

  // ---- store
#pragma unroll
  for (int mb = 0; mb < 2; mb++)
#pragma unroll
    for (int r = 0; r < 4; r++)
      out[(size_t)(base + wr * 32 + mb * 16 + quad * 4 + r) * U_DIM + u] = oacc[mb * 4 + r];
}

extern "C" void kernel_launch(void* const* d_in, const int* in_sizes, int n_in,
                              void* d_out, int out_size, void* d_ws, size_t ws_size,
                              hipStream_t stream) {
  const float* x  = (const float*)d_in[0];
  const float* Wg = (const float*)d_in[1];
  const float* bg = (const float*)d_in[2];
  const float* We = (const float*)d_in[3];
  const float* be = (const float*)d_in[4];
  unsigned short* wsWe = (unsigned short*)d_ws;              // 512 KB
  unsigned short* wsWg = wsWe + E_DIM * U_DIM * F_DIM;       // +8 KB
  (void)in_sizes; (void)n_in; (void)out_size; (void)ws_size;

  moe_prep<<<130, 256, 0, stream>>>(Wg, We, wsWe, wsWg);
  moe_main<<<N_TOK / 64, 512, 0, stream>>>(x, bg, be, wsWe, wsWg, (float*)d_out);
}